// Round 1
// baseline (963.880 us; speedup 1.0000x reference)
//
#include <hip/hip_runtime.h>

typedef unsigned short u16;
typedef unsigned int u32;
typedef __attribute__((ext_vector_type(8))) short bf16x8;
typedef __attribute__((ext_vector_type(4))) float f32x4;

#define AS1 __attribute__((address_space(1)))
#define AS3 __attribute__((address_space(3)))

__device__ __forceinline__ void async16(const void* g, void* l) {
  __builtin_amdgcn_global_load_lds((const AS1 void*)g, (AS3 void*)l, 16, 0, 0);
}

__device__ __forceinline__ u16 f2bf(float f) {
  union { float f; u32 u; } v; v.f = f;
  u32 u = v.u + 0x7fffu + ((v.u >> 16) & 1u);
  return (u16)(u >> 16);
}
__device__ __forceinline__ float bf2f(u16 h) {
  union { u32 u; float f; } v; v.u = ((u32)h) << 16;
  return v.f;
}

#define XT_STRIDE_B 57600   // 15*15*256 (padded NHWC, row/col 0 are the zero pad)
#define QKV_PER_B   37632   // 768*49

// ---------------- kernel 1: zero xt pad cells + stats -----------------------
__global__ __launch_bounds__(256) void k_zero(u16* __restrict__ xt, float* __restrict__ stats) {
  int u = blockIdx.x * 256 + threadIdx.x;        // 1024*29*32 units, exact grid
  int b = u / 928;
  int r = u - b * 928;
  int cell = r >> 5, c8 = r & 31;
  int ih = (cell < 15) ? 0 : (cell - 14);
  int iw = (cell < 15) ? cell : 0;
  int off = b * XT_STRIDE_B + ih * 3840 + iw * 256 + c8 * 8;
  uint4 z; z.x = 0u; z.y = 0u; z.z = 0u; z.w = 0u;
  *(uint4*)(xt + off) = z;
  if (blockIdx.x == 0 && threadIdx.x < 128) {
    float4 zf; zf.x = 0.f; zf.y = 0.f; zf.z = 0.f; zf.w = 0.f;
    ((float4*)stats)[threadIdx.x] = zf;
  }
}

// ---------------- kernel 2: weight repack OIHW fp32 -> [768][(khw,c)] bf16 ---
__global__ __launch_bounds__(256) void k_wprep(const float* __restrict__ w, u16* __restrict__ w2) {
  int e = (blockIdx.x * 256 + threadIdx.x) * 2;  // < 1769472, exact grid
  int n = e / 2304;
  int kk = e - n * 2304;
  int khw = kk >> 8, c = kk & 255;
  int s = n * 2304 + c * 9 + khw;
  u32 o = (u32)f2bf(w[s]) | ((u32)f2bf(w[s + 9]) << 16);
  *(u32*)(w2 + e) = o;
}

// ---------------- kernel 3: x NCHW fp32 -> padded NHWC bf16 ------------------
__global__ __launch_bounds__(256) void k_xprep(const float* __restrict__ x, u16* __restrict__ xt) {
  __shared__ u16 tile[196 * 68];                 // pitch 68: 2-way-max bank aliasing
  int b = blockIdx.x >> 2, ct = blockIdx.x & 3;
  int t = threadIdx.x;
  const float* xb = x + b * 50176 + ct * 64 * 196;
  #pragma unroll
  for (int it = 0; it < 49; ++it) {
    int e = t + it * 256;                        // coalesced fp32 read
    int cs = e / 196, hw = e - cs * 196;
    tile[hw * 68 + cs] = f2bf(xb[e]);
  }
  __syncthreads();
  u16* xtb = xt + b * XT_STRIDE_B + ct * 64;
  for (int o = t; o < 1568; o += 256) {
    int hw = o >> 3, c0 = (o & 7) * 8;
    int ih = hw / 14, iw = hw - ih * 14;
    const uint2* p = (const uint2*)&tile[hw * 68 + c0];   // 8B-aligned
    uint2 lo = p[0], hi = p[1];
    uint4 v; v.x = lo.x; v.y = lo.y; v.z = hi.x; v.w = hi.y;
    *(uint4*)(xtb + (ih + 1) * 3840 + (iw + 1) * 256 + c0) = v;
  }
}

// ---------------- kernel 4: implicit-GEMM conv, bf16 MFMA --------------------
// C[m=(b,oh,ow)][n] = sum_k A[m][k]*W[n][k], k=(kh,kw,c), M=50176 N=768 K=2304
// 128x128 tile, BK=64, 4 waves 2x2, mfma_f32_16x16x32_bf16, global_load_lds x16
__global__ __launch_bounds__(256, 2) void k_conv(const u16* __restrict__ xt,
                                                 const u16* __restrict__ w2,
                                                 u16* __restrict__ qkv) {
  __shared__ u16 As[128 * 64];
  __shared__ u16 Bs[128 * 64];
  int tid = threadIdx.x;
  int mtile = blockIdx.x / 6;
  int ntile = blockIdx.x - mtile * 6;
  int m0 = mtile * 128, n0 = ntile * 128;

  // staging: thread t stages 16B chunks (t + i*256); slot s holds row r=s>>3,
  // global sub = (s&7) ^ (r&7)  (XOR swizzle -> conflict-free ds_read_b128)
  int r0 = tid >> 3;
  int sub = (tid & 7) ^ (r0 & 7);
  int gA[4], gB[4];
  #pragma unroll
  for (int i = 0; i < 4; ++i) {
    int m = m0 + r0 + i * 32;
    int b = m / 49, p = m - b * 49;
    int oh = p / 7, ow = p - oh * 7;
    gA[i] = b * XT_STRIDE_B + oh * 7680 + ow * 512 + sub * 8;  // (2oh)*3840+(2ow)*256
    gB[i] = (n0 + r0 + i * 32) * 2304 + sub * 8;
  }

  int lane = tid & 63, wave = tid >> 6;
  int wm = (wave >> 1) * 64, wn = (wave & 1) * 64;
  int lm = lane & 15, lq = lane >> 4;

  int aoff[4][2], boff[4][2];
  #pragma unroll
  for (int i = 0; i < 4; ++i) {
    int mr = wm + i * 16 + lm;
    int nr = wn + i * 16 + lm;
    #pragma unroll
    for (int ks = 0; ks < 2; ++ks) {
      aoff[i][ks] = (mr * 8 + ((ks * 4 + lq) ^ (mr & 7))) * 8;
      boff[i][ks] = (nr * 8 + ((ks * 4 + lq) ^ (nr & 7))) * 8;
    }
  }

  f32x4 acc[4][4];
  #pragma unroll
  for (int i = 0; i < 4; ++i)
    #pragma unroll
    for (int j = 0; j < 4; ++j)
      acc[i][j] = (f32x4){0.f, 0.f, 0.f, 0.f};

  for (int kb = 0; kb < 36; ++kb) {
    int khw = kb >> 2;
    int kh = khw / 3;
    int kw = khw - kh * 3;
    int koffA = kh * 3840 + kw * 256 + ((kb & 3) << 6);
    int koffB = kb << 6;
    #pragma unroll
    for (int i = 0; i < 4; ++i) {
      async16(xt + gA[i] + koffA, As + (tid + i * 256) * 8);
      async16(w2 + gB[i] + koffB, Bs + (tid + i * 256) * 8);
    }
    __syncthreads();
    #pragma unroll
    for (int ks = 0; ks < 2; ++ks) {
      bf16x8 af[4], bfr[4];
      #pragma unroll
      for (int i = 0; i < 4; ++i) af[i] = *(const bf16x8*)(As + aoff[i][ks]);
      #pragma unroll
      for (int j = 0; j < 4; ++j) bfr[j] = *(const bf16x8*)(Bs + boff[j][ks]);
      #pragma unroll
      for (int i = 0; i < 4; ++i)
        #pragma unroll
        for (int j = 0; j < 4; ++j)
          acc[i][j] = __builtin_amdgcn_mfma_f32_16x16x32_bf16(af[i], bfr[j], acc[i][j], 0, 0, 0);
    }
    __syncthreads();
  }

  // epilogue: qkv[b][n][p] bf16  (C/D layout: col n = lane&15, row m = lq*4+r)
  #pragma unroll
  for (int i = 0; i < 4; ++i) {
    int mb = m0 + wm + i * 16 + lq * 4;
    #pragma unroll
    for (int r = 0; r < 4; ++r) {
      int m = mb + r;
      int b = m / 49, p = m - b * 49;
      int ob = b * QKV_PER_B + p;
      #pragma unroll
      for (int j = 0; j < 4; ++j) {
        int n = n0 + wn + j * 16 + lm;
        qkv[ob + n * 49] = f2bf(acc[i][j][r]);
      }
    }
  }
}

// ---------------- kernel 5: windowed attention per (b, head) -----------------
// q[n][d]=qkv_flat[b][n*768+h*32+d] (k:+256, v:+512); fuses BN-stat atomics
__global__ __launch_bounds__(256) void k_attn(const u16* __restrict__ qkv,
                                              const float* __restrict__ rpb,
                                              float* __restrict__ attn,
                                              float* __restrict__ stats) {
  __shared__ float qs[49 * 33], ks[49 * 33], vs[49 * 33];
  __shared__ float ss[49 * 53];
  __shared__ float rpbs[169];
  __shared__ float rsum[49];
  __shared__ float csum[32], csq[32];

  int b = blockIdx.x >> 3, h = blockIdx.x & 7;
  int t = threadIdx.x;
  int base = b * QKV_PER_B + h * 32;

  if (t < 169) rpbs[t] = rpb[t * 8 + h];
  if (t < 32) { csum[t] = 0.f; csq[t] = 0.f; }
  for (int e = t; e < 1568; e += 256) {
    int n = e >> 5, d = e & 31;
    int gi = base + n * 768 + d;
    qs[n * 33 + d] = bf2f(qkv[gi]) * 0.17677669529663687f;  // hd^-0.5
    ks[n * 33 + d] = bf2f(qkv[gi + 256]);
    vs[n * 33 + d] = bf2f(qkv[gi + 512]);
  }
  __syncthreads();
  for (int e = t; e < 2401; e += 256) {
    int j = e / 49, i = e - j * 49;
    float s = 0.f;
    #pragma unroll
    for (int d = 0; d < 32; ++d) s += qs[i * 33 + d] * ks[j * 33 + d];
    int ridx = (i / 7 - j / 7 + 6) * 13 + (i % 7 - j % 7 + 6);
    ss[i * 53 + j] = s + rpbs[ridx];
  }
  __syncthreads();
  if (t < 49) {                                   // softmax rows
    float m = -1e30f;
    for (int j = 0; j < 49; ++j) m = fmaxf(m, ss[t * 53 + j]);
    float sm = 0.f;
    for (int j = 0; j < 49; ++j) {
      float e2 = __expf(ss[t * 53 + j] - m);
      ss[t * 53 + j] = e2;
      sm += e2;
    }
    rsum[t] = 1.f / sm;
  }
  __syncthreads();
  for (int e = t; e < 1568; e += 256) {
    int i = e >> 5, d = e & 31;
    float o = 0.f;
    for (int m2 = 0; m2 < 49; ++m2) o += ss[i * 53 + m2] * vs[m2 * 33 + d];
    o *= rsum[i];
    attn[b * 12544 + (h * 32 + d) * 49 + i] = o;  // [B][C][49], c = h*32+d, p = i
    atomicAdd(&csum[d], o);
    atomicAdd(&csq[d], o * o);
  }
  __syncthreads();
  if (t < 32) {
    atomicAdd(&stats[h * 32 + t], csum[t]);
    atomicAdd(&stats[256 + h * 32 + t], csq[t]);
  }
}

// ---------------- kernel 6: upsample 2x nearest + BN -------------------------
__global__ __launch_bounds__(256) void k_final(const float* __restrict__ attn,
                                               const float* __restrict__ stats,
                                               const float* __restrict__ gamma,
                                               const float* __restrict__ beta,
                                               float* __restrict__ out) {
  int pi = blockIdx.x * 256 + threadIdx.x;        // < 25690112, exact grid
  int j = pi % 7;
  int rest = pi / 7;                              // (b*256+c)*14 + y
  int y = rest % 14;
  int bc = rest / 14;
  int c = bc & 255;
  const float inv = 1.f / 50176.f;                // stats over 7x7 == over 14x14
  float mean = stats[c] * inv;
  float var = stats[256 + c] * inv - mean * mean;
  float rstd = rsqrtf(var + 1e-5f);
  float A = gamma[c] * rstd;
  float Bv = beta[c] - mean * A;
  float v = attn[bc * 49 + (y >> 1) * 7 + j] * A + Bv;
  float2 o; o.x = v; o.y = v;
  ((float2*)out)[pi] = o;
}

extern "C" void kernel_launch(void* const* d_in, const int* in_sizes, int n_in,
                              void* d_out, int out_size, void* d_ws, size_t ws_size,
                              hipStream_t stream) {
  const float* x     = (const float*)d_in[0];
  const float* w     = (const float*)d_in[1];
  const float* rpb   = (const float*)d_in[2];
  const float* gamma = (const float*)d_in[3];
  const float* beta  = (const float*)d_in[4];
  float* out = (float*)d_out;

  char* ws = (char*)d_ws;
  u16*   xt    = (u16*)ws;                      // 117,964,800 B (padded NHWC bf16)
  float* attn  = (float*)ws;                    // aliases xt (dead after k_conv)
  u16*   w2    = (u16*)(ws + 117964800);        //   3,538,944 B
  u16*   qkv   = (u16*)(ws + 121503744);        //  77,070,336 B (bf16 [B][768][49])
  float* stats = (float*)(ws + 198574080);      //       2,048 B  (total ~198.6 MB)

  k_zero <<<3712,   256, 0, stream>>>(xt, stats);
  k_wprep<<<3456,   256, 0, stream>>>(w, w2);
  k_xprep<<<4096,   256, 0, stream>>>(x, xt);
  k_conv <<<2352,   256, 0, stream>>>(xt, w2, qkv);
  k_attn <<<8192,   256, 0, stream>>>(qkv, rpb, attn, stats);
  k_final<<<100352, 256, 0, stream>>>(attn, stats, gamma, beta, out);
}

// Round 3
// 702.122 us; speedup vs baseline: 1.3728x; 1.3728x over previous
//
#include <hip/hip_runtime.h>

typedef unsigned short u16;
typedef unsigned int u32;
typedef __attribute__((ext_vector_type(8))) short bf16x8;
typedef __attribute__((ext_vector_type(4))) float f32x4;

#define AS1 __attribute__((address_space(1)))
#define AS3 __attribute__((address_space(3)))

__device__ __forceinline__ void async16(const void* g, void* l) {
  __builtin_amdgcn_global_load_lds((const AS1 void*)g, (AS3 void*)l, 16, 0, 0);
}

__device__ __forceinline__ u16 f2bf(float f) {
  union { float f; u32 u; } v; v.f = f;
  u32 u = v.u + 0x7fffu + ((v.u >> 16) & 1u);
  return (u16)(u >> 16);
}
__device__ __forceinline__ float bf2f(u16 h) {
  union { u32 u; float f; } v; v.u = ((u32)h) << 16;
  return v.f;
}

#define XT_STRIDE_B 57600   // 15*15*256 (padded NHWC, row/col 0 are the zero pad)
#define QKV_PER_B   37632   // 768*49 (flat [3C][49] per batch, row-major)

// ---------------- kernel 1: zero xt pad cells + stats -----------------------
__global__ __launch_bounds__(256) void k_zero(u16* __restrict__ xt, float* __restrict__ stats) {
  int u = blockIdx.x * 256 + threadIdx.x;        // 1024*29*32 units, exact grid
  int b = u / 928;
  int r = u - b * 928;
  int cell = r >> 5, c8 = r & 31;
  int ih = (cell < 15) ? 0 : (cell - 14);
  int iw = (cell < 15) ? cell : 0;
  int off = b * XT_STRIDE_B + ih * 3840 + iw * 256 + c8 * 8;
  uint4 z; z.x = 0u; z.y = 0u; z.z = 0u; z.w = 0u;
  *(uint4*)(xt + off) = z;
  if (blockIdx.x == 0 && threadIdx.x < 128) {
    float4 zf; zf.x = 0.f; zf.y = 0.f; zf.z = 0.f; zf.w = 0.f;
    ((float4*)stats)[threadIdx.x] = zf;
  }
}

// ---------------- kernel 2: weight repack OIHW fp32 -> [768][(khw,c)] bf16 ---
__global__ __launch_bounds__(256) void k_wprep(const float* __restrict__ w, u16* __restrict__ w2) {
  int e = (blockIdx.x * 256 + threadIdx.x) * 2;  // < 1769472, exact grid
  int n = e / 2304;
  int kk = e - n * 2304;
  int khw = kk >> 8, c = kk & 255;
  int s = n * 2304 + c * 9 + khw;
  u32 o = (u32)f2bf(w[s]) | ((u32)f2bf(w[s + 9]) << 16);
  *(u32*)(w2 + e) = o;
}

// ---------------- kernel 3: x NCHW fp32 -> padded NHWC bf16 ------------------
__global__ __launch_bounds__(256) void k_xprep(const float* __restrict__ x, u16* __restrict__ xt) {
  __shared__ u16 tile[196 * 68];
  int b = blockIdx.x >> 2, ct = blockIdx.x & 3;
  int t = threadIdx.x;
  const float* xb = x + b * 50176 + ct * 64 * 196;
  #pragma unroll
  for (int it = 0; it < 49; ++it) {
    int e = t + it * 256;
    int cs = e / 196, hw = e - cs * 196;
    tile[hw * 68 + cs] = f2bf(xb[e]);
  }
  __syncthreads();
  u16* xtb = xt + b * XT_STRIDE_B + ct * 64;
  for (int o = t; o < 1568; o += 256) {
    int hw = o >> 3, c0 = (o & 7) * 8;
    int ih = hw / 14, iw = hw - ih * 14;
    const uint2* p = (const uint2*)&tile[hw * 68 + c0];
    uint2 lo = p[0], hi = p[1];
    uint4 v; v.x = lo.x; v.y = lo.y; v.z = hi.x; v.w = hi.y;
    *(uint4*)(xtb + (ih + 1) * 3840 + (iw + 1) * 256 + c0) = v;
  }
}

// ---------------- kernel 4: implicit-GEMM conv, bf16 MFMA --------------------
// C[m=(b,oh,ow)][n] = sum_k A[m][k]*W[n][k], k=(kh,kw,c), M=50176 N=768 K=2304
// Output: natural flat layout qkv[b*37632 + n*49 + p] (bf16) — the faithful
// torch reshape is a flat reinterpretation of this buffer.
// Grid swizzle: 2352 = 49 groups x (8 mtiles x 6 ntiles); the 6 ntile-siblings
// sharing one A-panel are 8 blockIdx apart -> same XCD (round-robin) -> A hits L2.
__global__ __launch_bounds__(256, 3) void k_conv(const u16* __restrict__ xt,
                                                 const u16* __restrict__ w2,
                                                 u16* __restrict__ qkv) {
  __shared__ u16 As[128 * 64];
  __shared__ u16 Bs[128 * 64];
  int tid = threadIdx.x;
  int g = blockIdx.x / 48;
  int r48 = blockIdx.x - g * 48;
  int mtile = g * 8 + (r48 & 7);
  int ntile = r48 >> 3;
  int m0 = mtile * 128, n0 = ntile * 128;

  int r0 = tid >> 3;
  int sub = (tid & 7) ^ (r0 & 7);
  int gA[4], gB[4];
  #pragma unroll
  for (int i = 0; i < 4; ++i) {
    int m = m0 + r0 + i * 32;
    int b = m / 49, p = m - b * 49;
    int oh = p / 7, ow = p - oh * 7;
    gA[i] = b * XT_STRIDE_B + oh * 7680 + ow * 512 + sub * 8;
    gB[i] = (n0 + r0 + i * 32) * 2304 + sub * 8;
  }

  int lane = tid & 63, wave = tid >> 6;
  int wm = (wave >> 1) * 64, wn = (wave & 1) * 64;
  int lm = lane & 15, lq = lane >> 4;

  int aoff[4][2], boff[4][2];
  #pragma unroll
  for (int i = 0; i < 4; ++i) {
    int mr = wm + i * 16 + lm;
    int nr = wn + i * 16 + lm;
    #pragma unroll
    for (int ks = 0; ks < 2; ++ks) {
      aoff[i][ks] = (mr * 8 + ((ks * 4 + lq) ^ (mr & 7))) * 8;
      boff[i][ks] = (nr * 8 + ((ks * 4 + lq) ^ (nr & 7))) * 8;
    }
  }

  f32x4 acc[4][4];
  #pragma unroll
  for (int i = 0; i < 4; ++i)
    #pragma unroll
    for (int j = 0; j < 4; ++j)
      acc[i][j] = (f32x4){0.f, 0.f, 0.f, 0.f};

  for (int kb = 0; kb < 36; ++kb) {
    int khw = kb >> 2;
    int kh = khw / 3;
    int kw = khw - kh * 3;
    int koffA = kh * 3840 + kw * 256 + ((kb & 3) << 6);
    int koffB = kb << 6;
    #pragma unroll
    for (int i = 0; i < 4; ++i) {
      async16(xt + gA[i] + koffA, As + (tid + i * 256) * 8);
      async16(w2 + gB[i] + koffB, Bs + (tid + i * 256) * 8);
    }
    __syncthreads();
    #pragma unroll
    for (int ks = 0; ks < 2; ++ks) {
      bf16x8 af[4], bfr[4];
      #pragma unroll
      for (int i = 0; i < 4; ++i) af[i] = *(const bf16x8*)(As + aoff[i][ks]);
      #pragma unroll
      for (int j = 0; j < 4; ++j) bfr[j] = *(const bf16x8*)(Bs + boff[j][ks]);
      #pragma unroll
      for (int i = 0; i < 4; ++i)
        #pragma unroll
        for (int j = 0; j < 4; ++j)
          acc[i][j] = __builtin_amdgcn_mfma_f32_16x16x32_bf16(af[i], bfr[j], acc[i][j], 0, 0, 0);
    }
    __syncthreads();
  }

  // epilogue (R1-proven): qkv[b*37632 + n*49 + p] (C/D: col=lane&15, row=lq*4+r)
  #pragma unroll
  for (int i = 0; i < 4; ++i) {
    int mb = m0 + wm + i * 16 + lq * 4;
    #pragma unroll
    for (int r = 0; r < 4; ++r) {
      int m = mb + r;
      int b = m / 49, p = m - b * 49;
      int ob = b * QKV_PER_B + p;
      #pragma unroll
      for (int j = 0; j < 4; ++j) {
        int n = n0 + wn + j * 16 + lm;
        qkv[ob + n * 49] = f2bf(acc[i][j][r]);
      }
    }
  }
}

// ---------------- kernel 5: windowed attention, MFMA, 1 wave per (b,h) -------
// Flat layout: q(n_,d) = G[b*37632 + n_*768 + h*32 + d], k: +256, v: +512.
// Computes O^T = V^T P^T -> attn[b][c=h*32+d][p] fp32; fuses BN-stat atomics.
__global__ __launch_bounds__(256) void k_attn(const u16* __restrict__ G,
                                              const float* __restrict__ rpb,
                                              float* __restrict__ attn,
                                              float* __restrict__ stats) {
  __shared__ __align__(16) u16 Ps[4][64 * 72];
  __shared__ __align__(16) u16 Vs[4][32 * 72];
  __shared__ float rsum[4][64];
  __shared__ float rpbs[169];
  __shared__ float csum[32], csq[32];

  int t = threadIdx.x;
  int h = blockIdx.x >> 8;                       // all 4 waves share head h
  int bq = blockIdx.x & 255;
  int w = t >> 6, lane = t & 63;
  int lm = lane & 15, lq = lane >> 4;
  int b = bq * 4 + w;

  if (t < 169) rpbs[t] = rpb[t * 8 + h];
  if (t < 32) { csum[t] = 0.f; csq[t] = 0.f; }
  __syncthreads();

  u16* Pw = Ps[w];
  u16* Vw = Vs[w];
  float* rs = rsum[w];
  const u16* Gb = G + (size_t)b * QKV_PER_B;

  // zero V pad columns 49..63 (keys) to keep mfma clean
  for (int e = lane; e < 480; e += 64) {
    int d = e / 15, c = 49 + (e - d * 15);
    Vw[d * 72 + c] = 0;
  }
  // stage V transposed: flat (p,d) -> Vs[d][p]
  {
    const u32* vg = (const u32*)Gb;
    int cbase = 256 + h * 16;                    // (512 + h*32)/2
    for (int e = lane; e < 784; e += 64) {
      int p = e >> 4, dp = e & 15;
      u32 vv = vg[p * 384 + cbase + dp];
      Vw[(2 * dp) * 72 + p] = (u16)vv;
      Vw[(2 * dp + 1) * 72 + p] = (u16)(vv >> 16);
    }
  }

  // Q/K fragments: direct global dwordx4; A/B frag = [row=lane&15][k=lq*8..+8]
  bf16x8 aq[4], bk[4];
  #pragma unroll
  for (int i = 0; i < 4; ++i) {
    int p = i * 16 + lm; p = (p > 48) ? 48 : p;
    aq[i] = *(const bf16x8*)(Gb + p * 768 + h * 32 + lq * 8);
    bk[i] = *(const bf16x8*)(Gb + p * 768 + 256 + h * 32 + lq * 8);
  }

  f32x4 accs[4][4];
  #pragma unroll
  for (int i = 0; i < 4; ++i)
    #pragma unroll
    for (int j = 0; j < 4; ++j)
      accs[i][j] = (f32x4){0.f, 0.f, 0.f, 0.f};
  #pragma unroll
  for (int i = 0; i < 4; ++i)
    #pragma unroll
    for (int j = 0; j < 4; ++j)
      accs[i][j] = __builtin_amdgcn_mfma_f32_16x16x32_bf16(aq[i], bk[j], accs[i][j], 0, 0, 0);

  // softmax over key dim (scale + rel-pos bias); reduce across lm (16 lanes)
  const float SCALE = 0.17677669529663687f;
  #pragma unroll
  for (int i = 0; i < 4; ++i) {
    #pragma unroll
    for (int r = 0; r < 4; ++r) {
      int row = i * 16 + lq * 4 + r;             // query index (49..63 dup of 48)
      int rc = (row > 48) ? 48 : row;
      int ri = rc / 7, rj = rc - ri * 7;
      float x[4];
      #pragma unroll
      for (int j = 0; j < 4; ++j) {
        int col = j * 16 + lm;                   // key index
        int cc = (col > 48) ? 48 : col;
        int ci = cc / 7, cj = cc - ci * 7;
        int ridx = (ri - ci + 6) * 13 + (rj - cj + 6);
        x[j] = accs[i][j][r] * SCALE + rpbs[ridx];
      }
      if (lm) x[3] = -3.0e38f;                   // mask keys 49..63
      float mx = fmaxf(fmaxf(x[0], x[1]), fmaxf(x[2], x[3]));
      mx = fmaxf(mx, __shfl_xor(mx, 1));
      mx = fmaxf(mx, __shfl_xor(mx, 2));
      mx = fmaxf(mx, __shfl_xor(mx, 4));
      mx = fmaxf(mx, __shfl_xor(mx, 8));
      float e0 = __expf(x[0] - mx), e1 = __expf(x[1] - mx), e2 = __expf(x[2] - mx);
      float e3 = lm ? 0.f : __expf(x[3] - mx);
      float sm = e0 + e1 + e2 + e3;
      sm += __shfl_xor(sm, 1);
      sm += __shfl_xor(sm, 2);
      sm += __shfl_xor(sm, 4);
      sm += __shfl_xor(sm, 8);
      if (lm == 0) rs[row] = 1.0f / sm;
      u16* pr = Pw + row * 72;
      pr[lm] = f2bf(e0);
      pr[16 + lm] = f2bf(e1);
      pr[32 + lm] = f2bf(e2);
      pr[48 + lm] = f2bf(e3);
    }
  }

  // O^T = V^T P^T : A = Vs[d][key] (M=32), B = Ps[query][key] (N=64), K=64
  f32x4 acc2[2][4];
  #pragma unroll
  for (int i2 = 0; i2 < 2; ++i2)
    #pragma unroll
    for (int j = 0; j < 4; ++j)
      acc2[i2][j] = (f32x4){0.f, 0.f, 0.f, 0.f};
  #pragma unroll
  for (int ks = 0; ks < 2; ++ks) {
    bf16x8 av[2], bp[4];
    #pragma unroll
    for (int i2 = 0; i2 < 2; ++i2)
      av[i2] = *(const bf16x8*)(Vw + (i2 * 16 + lm) * 72 + ks * 32 + lq * 8);
    #pragma unroll
    for (int j = 0; j < 4; ++j)
      bp[j] = *(const bf16x8*)(Pw + (j * 16 + lm) * 72 + ks * 32 + lq * 8);
    #pragma unroll
    for (int i2 = 0; i2 < 2; ++i2)
      #pragma unroll
      for (int j = 0; j < 4; ++j)
        acc2[i2][j] = __builtin_amdgcn_mfma_f32_16x16x32_bf16(av[i2], bp[j], acc2[i2][j], 0, 0, 0);
  }

  // normalize, store O^T as attn[b][c=h*32+d][p], fuse BN stats
  float invj[4];
  #pragma unroll
  for (int j = 0; j < 4; ++j) invj[j] = rs[j * 16 + lm];
  float* ob = attn + (size_t)(b * 8 + h) * 1568;
  #pragma unroll
  for (int i2 = 0; i2 < 2; ++i2) {
    #pragma unroll
    for (int r = 0; r < 4; ++r) {
      int row_d = i2 * 16 + lq * 4 + r;          // d in [0,32)
      float sS = 0.f, sQ = 0.f;
      #pragma unroll
      for (int j = 0; j < 4; ++j) {
        int col = j * 16 + lm;                   // query index
        bool valid = (col < 49);
        float v = acc2[i2][j][r] * invj[j];
        float vm = valid ? v : 0.f;
        if (valid) ob[row_d * 49 + col] = v;
        sS += vm; sQ += vm * vm;
      }
      sS += __shfl_xor(sS, 1); sQ += __shfl_xor(sQ, 1);
      sS += __shfl_xor(sS, 2); sQ += __shfl_xor(sQ, 2);
      sS += __shfl_xor(sS, 4); sQ += __shfl_xor(sQ, 4);
      sS += __shfl_xor(sS, 8); sQ += __shfl_xor(sQ, 8);
      if (lm == 0) {
        atomicAdd(&csum[row_d], sS);
        atomicAdd(&csq[row_d], sQ);
      }
    }
  }
  __syncthreads();
  if (t < 32) {
    atomicAdd(&stats[h * 32 + t], csum[t]);
    atomicAdd(&stats[256 + h * 32 + t], csq[t]);
  }
}

// ---------------- kernel 6: upsample 2x nearest + BN -------------------------
__global__ __launch_bounds__(256) void k_final(const float* __restrict__ attn,
                                               const float* __restrict__ stats,
                                               const float* __restrict__ gamma,
                                               const float* __restrict__ beta,
                                               float* __restrict__ out) {
  int pi = blockIdx.x * 256 + threadIdx.x;        // < 25690112, exact grid
  int j = pi % 7;
  int rest = pi / 7;                              // (b*256+c)*14 + y
  int y = rest % 14;
  int bc = rest / 14;
  int c = bc & 255;
  const float inv = 1.f / 50176.f;
  float mean = stats[c] * inv;
  float var = stats[256 + c] * inv - mean * mean;
  float rstd = rsqrtf(var + 1e-5f);
  float A = gamma[c] * rstd;
  float Bv = beta[c] - mean * A;
  float v = attn[bc * 49 + (y >> 1) * 7 + j] * A + Bv;
  float2 o; o.x = v; o.y = v;
  ((float2*)out)[pi] = o;
}

extern "C" void kernel_launch(void* const* d_in, const int* in_sizes, int n_in,
                              void* d_out, int out_size, void* d_ws, size_t ws_size,
                              hipStream_t stream) {
  const float* x     = (const float*)d_in[0];
  const float* w     = (const float*)d_in[1];
  const float* rpb   = (const float*)d_in[2];
  const float* gamma = (const float*)d_in[3];
  const float* beta  = (const float*)d_in[4];
  float* out = (float*)d_out;

  char* ws = (char*)d_ws;
  u16*   xt    = (u16*)ws;                      // 117,964,800 B (padded NHWC bf16)
  float* attn  = (float*)ws;                    // aliases xt (dead after k_conv)
  u16*   w2    = (u16*)(ws + 117964800);        //   3,538,944 B
  u16*   qkv   = (u16*)(ws + 121503744);        //  77,070,336 B (flat [b][768][49])
  float* stats = (float*)(ws + 198574080);      //       2,048 B

  k_zero <<<3712,   256, 0, stream>>>(xt, stats);
  k_wprep<<<3456,   256, 0, stream>>>(w, w2);
  k_xprep<<<4096,   256, 0, stream>>>(x, xt);
  k_conv <<<2352,   256, 0, stream>>>(xt, w2, qkv);
  k_attn <<<2048,   256, 0, stream>>>(qkv, rpb, attn, stats);
  k_final<<<100352, 256, 0, stream>>>(attn, stats, gamma, beta, out);
}